// Round 3
// baseline (655.742 us; speedup 1.0000x reference)
//
#include <hip/hip_runtime.h>

// SDPAttention, softmax over the QUERY axis (dim=1), strict causal mask.
// B=16, S=2048, D=128. Inputs fp32, output fp32 (established: R1 NaN = fp32
// inputs; R2 scrambled-bf16-as-fp32 absmax = fp32 output).
//
// convert: Q,K -> hi/lo bf16 split (hi=RNE(x), lo=RNE(x-hi)).
// vtrans:  V -> V^T bf16 (b,d,k) so PV B-fragments are contiguous 16B loads.
// pass1:   column stats m[b,k]=max_q s, l[b,k]=sum_q exp(s-m)  (q>=k only).
// pass2:   out[b,q,:] = sum_k exp(s[q,k]-m[k])/l[k] * V[b,k,:].
// Scores use 3-term split MFMA (qh*kh + ql*kh + qh*kl) ~ fp32 precision.
//
// ws: m(128K) | l(128K) | Qhi|Qlo|Khi|Klo|Vt (8MB each) = 40.25MB

#define B_ 16
#define S_ 2048
#define D_ 128
#define SCALE 0.08838834764831845f /* 1/sqrt(128) */
#define NEG_BIG -1e30f

typedef short bf16x8 __attribute__((ext_vector_type(8)));
typedef float f32x4 __attribute__((ext_vector_type(4)));
typedef unsigned short u16x4 __attribute__((ext_vector_type(4)));

static __device__ __forceinline__ unsigned short f2bf(float f) {
  unsigned int u = __builtin_bit_cast(unsigned int, f);
  u += 0x7FFFu + ((u >> 16) & 1u);  // RNE
  return (unsigned short)(u >> 16);
}
static __device__ __forceinline__ float bf2f(unsigned short h) {
  return __builtin_bit_cast(float, (unsigned int)h << 16);
}

// --------------------------------------------------------------- convert ----
// grid (4096, 2): y=0 -> Q, y=1 -> K. One thread per 4 elements.
__global__ __launch_bounds__(256) void sdpa_convert(
    const float* __restrict__ Qr, const float* __restrict__ Kr,
    unsigned short* __restrict__ Qhi, unsigned short* __restrict__ Qlo,
    unsigned short* __restrict__ Khi, unsigned short* __restrict__ Klo) {
  const size_t t = (size_t)blockIdx.x * 256 + threadIdx.x;
  const float* src = blockIdx.y ? Kr : Qr;
  unsigned short* hi = blockIdx.y ? Khi : Qhi;
  unsigned short* lo = blockIdx.y ? Klo : Qlo;
  f32x4 x = ((const f32x4*)src)[t];
  u16x4 ho, lv;
#pragma unroll
  for (int j = 0; j < 4; ++j) {
    unsigned short h = f2bf(x[j]);
    ho[j] = h;
    lv[j] = f2bf(x[j] - bf2f(h));
  }
  ((u16x4*)hi)[t] = ho;
  ((u16x4*)lo)[t] = lv;
}

// ---------------------------------------------------------------- vtrans ----
// LDS-tiled transpose: V[b][k][d] (fp32) -> Vt[b][d][k] (bf16). grid (S/32, B).
__global__ __launch_bounds__(256) void sdpa_vtrans(
    const float* __restrict__ Vr, unsigned short* __restrict__ Vt) {
  __shared__ unsigned short tile[D_][33];
  const int b = blockIdx.y, k0 = blockIdx.x * 32, tid = threadIdx.x;
#pragma unroll
  for (int it = 0; it < 4; ++it) {
    const int r = it * 8 + (tid >> 5);  // k within tile
    const int c4 = (tid & 31) * 4;      // d
    f32x4 x = *(const f32x4*)(Vr + ((size_t)(b * S_ + k0 + r)) * D_ + c4);
#pragma unroll
    for (int j = 0; j < 4; ++j) tile[c4 + j][r] = f2bf(x[j]);
  }
  __syncthreads();
#pragma unroll
  for (int it = 0; it < 4; ++it) {
    const int d = it * 32 + (tid >> 3);
    const int kq = (tid & 7) * 4;
    u16x4 o = {tile[d][kq], tile[d][kq + 1], tile[d][kq + 2], tile[d][kq + 3]};
    *(u16x4*)(Vt + ((size_t)(b * D_ + d)) * S_ + k0 + kq) = o;
  }
}

// ----------------------------------------------------------------- pass1 ----
// grid (S/64, B), block 256. Wave w owns 16 key-columns.
// MFMA 16x16x32: A[m=lane&15][k=quad*8+j]; B[k=quad*8+j][n=lane&15];
// C/D reg r -> D[row=quad*4+r][col=lane&15].
__global__ __launch_bounds__(256) void sdpa_pass1(
    const short* __restrict__ Qhi, const short* __restrict__ Qlo,
    const short* __restrict__ Khi, const short* __restrict__ Klo,
    float* __restrict__ m_ws, float* __restrict__ l_ws) {
  const int b = blockIdx.y;
  const int w = threadIdx.x >> 6;
  const int lane = threadIdx.x & 63;
  const int quad = lane >> 4;
  const int l15 = lane & 15;
  const int kc0 = blockIdx.x * 64 + w * 16;
  const int col = kc0 + l15;

  const size_t koff = ((size_t)b * S_ + col) * D_ + quad * 8;
  bf16x8 kh[4], kl[4];
#pragma unroll
  for (int c = 0; c < 4; ++c) {
    kh[c] = *(const bf16x8*)(Khi + koff + c * 32);
    kl[c] = *(const bf16x8*)(Klo + koff + c * 32);
  }

  float m = NEG_BIG, l = 0.f;
  const size_t qoff0 = ((size_t)b * S_ + l15) * D_ + quad * 8;

  for (int q0 = kc0; q0 < S_; q0 += 16) {  // only q >= kc0 can be unmasked
    const size_t qoff = qoff0 + (size_t)q0 * D_;
    f32x4 acc = {0.f, 0.f, 0.f, 0.f};
#pragma unroll
    for (int c = 0; c < 4; ++c) {
      bf16x8 qh = *(const bf16x8*)(Qhi + qoff + c * 32);
      bf16x8 ql = *(const bf16x8*)(Qlo + qoff + c * 32);
      acc = __builtin_amdgcn_mfma_f32_16x16x32_bf16(qh, kh[c], acc, 0, 0, 0);
      acc = __builtin_amdgcn_mfma_f32_16x16x32_bf16(ql, kh[c], acc, 0, 0, 0);
      acc = __builtin_amdgcn_mfma_f32_16x16x32_bf16(qh, kl[c], acc, 0, 0, 0);
    }
    float sv[4];
    float tmax = NEG_BIG;
#pragma unroll
    for (int r = 0; r < 4; ++r) {
      int q = q0 + quad * 4 + r;
      float s = acc[r] * SCALE;
      if (q < col) s = NEG_BIG;  // strict causal: k > q masked
      sv[r] = s;
      tmax = fmaxf(tmax, s);
    }
    tmax = fmaxf(tmax, __shfl_xor(tmax, 16, 64));
    tmax = fmaxf(tmax, __shfl_xor(tmax, 32, 64));
    float mnew = fmaxf(m, tmax);
    float tsum = 0.f;
#pragma unroll
    for (int r = 0; r < 4; ++r) tsum += __expf(sv[r] - mnew);
    tsum += __shfl_xor(tsum, 16, 64);
    tsum += __shfl_xor(tsum, 32, 64);
    l = l * __expf(m - mnew) + tsum;
    m = mnew;
  }
  if (quad == 0) {
    m_ws[b * S_ + col] = m;
    l_ws[b * S_ + col] = l;
  }
}

// ----------------------------------------------------------------- pass2 ----
// grid (S/64, B), block 256. Wave w owns 16 query-rows. Wave-private LDS.
__global__ __launch_bounds__(256) void sdpa_pass2(
    const short* __restrict__ Qhi, const short* __restrict__ Qlo,
    const short* __restrict__ Khi, const short* __restrict__ Klo,
    const unsigned short* __restrict__ Vt,
    const float* __restrict__ m_ws, const float* __restrict__ l_ws,
    float* __restrict__ Out) {
  __shared__ __align__(16) float Pbuf[4][16][36];
  const int b = blockIdx.y;
  const int w = threadIdx.x >> 6;
  const int lane = threadIdx.x & 63;
  const int quad = lane >> 4;
  const int l15 = lane & 15;
  const int qw0 = blockIdx.x * 64 + w * 16;

  const size_t qoff = ((size_t)b * S_ + qw0 + l15) * D_ + quad * 8;
  bf16x8 qh[4], ql[4];
#pragma unroll
  for (int c = 0; c < 4; ++c) {
    qh[c] = *(const bf16x8*)(Qhi + qoff + c * 32);
    ql[c] = *(const bf16x8*)(Qlo + qoff + c * 32);
  }

  f32x4 acc[8];
#pragma unroll
  for (int dt = 0; dt < 8; ++dt) acc[dt] = (f32x4){0.f, 0.f, 0.f, 0.f};

  const int qmax = qw0 + 15;
  const int rowq = qw0 + quad * 4;
  const float* mrow = m_ws + b * S_;
  const float* lrow = l_ws + b * S_;

  for (int kc = 0; kc <= qmax; kc += 32) {
#pragma unroll
    for (int sub = 0; sub < 2; ++sub) {
      const int colk = kc + sub * 16 + l15;
      const size_t koff = ((size_t)b * S_ + colk) * D_ + quad * 8;
      f32x4 sa = {0.f, 0.f, 0.f, 0.f};
#pragma unroll
      for (int c = 0; c < 4; ++c) {
        bf16x8 kh = *(const bf16x8*)(Khi + koff + c * 32);
        bf16x8 kl = *(const bf16x8*)(Klo + koff + c * 32);
        sa = __builtin_amdgcn_mfma_f32_16x16x32_bf16(qh[c], kh, sa, 0, 0, 0);
        sa = __builtin_amdgcn_mfma_f32_16x16x32_bf16(ql[c], kh, sa, 0, 0, 0);
        sa = __builtin_amdgcn_mfma_f32_16x16x32_bf16(qh[c], kl, sa, 0, 0, 0);
      }
      const float mc = mrow[colk];
      const float rl = 1.0f / lrow[colk];
#pragma unroll
      for (int r = 0; r < 4; ++r) {
        float p = (colk <= rowq + r) ? __expf(sa[r] * SCALE - mc) * rl : 0.f;
        Pbuf[w][quad * 4 + r][sub * 16 + l15] = p;  // C-layout -> LDS
      }
    }
    // C-layout (fp32, LDS) -> A-fragment (bf16, regs)
    const float* pr = &Pbuf[w][l15][quad * 8];
    f32x4 p0 = *(const f32x4*)(pr);
    f32x4 p1 = *(const f32x4*)(pr + 4);
    bf16x8 pa;
#pragma unroll
    for (int j = 0; j < 4; ++j) {
      pa[j] = (short)f2bf(p0[j]);
      pa[j + 4] = (short)f2bf(p1[j]);
    }
#pragma unroll
    for (int dt = 0; dt < 8; ++dt) {
      const unsigned short* vp =
          Vt + ((size_t)b * D_ + dt * 16 + l15) * S_ + kc + quad * 8;
      bf16x8 vf = *(const bf16x8*)(vp);
      acc[dt] = __builtin_amdgcn_mfma_f32_16x16x32_bf16(pa, vf, acc[dt], 0, 0, 0);
    }
  }
  // epilogue: C-layout -> fp32 global
#pragma unroll
  for (int r = 0; r < 4; ++r) {
    float* op = Out + ((size_t)b * S_ + rowq + r) * D_ + l15;
#pragma unroll
    for (int dt = 0; dt < 8; ++dt) op[dt * 16] = acc[dt][r];
  }
}

extern "C" void kernel_launch(void* const* d_in, const int* in_sizes, int n_in,
                              void* d_out, int out_size, void* d_ws, size_t ws_size,
                              hipStream_t stream) {
  char* w = (char*)d_ws;
  float* m_ws = (float*)w;
  float* l_ws = (float*)(w + 131072);
  char* p = w + 262144;
  const size_t TSZ = (size_t)B_ * S_ * D_ * 2;  // 8 MB per bf16 tensor
  unsigned short* Qhi = (unsigned short*)(p);
  unsigned short* Qlo = (unsigned short*)(p + TSZ);
  unsigned short* Khi = (unsigned short*)(p + 2 * TSZ);
  unsigned short* Klo = (unsigned short*)(p + 3 * TSZ);
  unsigned short* Vt  = (unsigned short*)(p + 4 * TSZ);

  sdpa_convert<<<dim3((B_ * S_ * D_ / 4) / 256, 2), 256, 0, stream>>>(
      (const float*)d_in[0], (const float*)d_in[1], Qhi, Qlo, Khi, Klo);
  sdpa_vtrans<<<dim3(S_ / 32, B_), 256, 0, stream>>>((const float*)d_in[2], Vt);
  sdpa_pass1<<<dim3(S_ / 64, B_), 256, 0, stream>>>(
      (const short*)Qhi, (const short*)Qlo, (const short*)Khi,
      (const short*)Klo, m_ws, l_ws);
  sdpa_pass2<<<dim3(S_ / 64, B_), 256, 0, stream>>>(
      (const short*)Qhi, (const short*)Qlo, (const short*)Khi,
      (const short*)Klo, Vt, m_ws, l_ws, (float*)d_out);
}

// Round 4
// 317.494 us; speedup vs baseline: 2.0654x; 2.0654x over previous
//
#include <hip/hip_runtime.h>

// SDPAttention, softmax over the QUERY axis (dim=1), strict causal mask.
// B=16, S=2048, D=128. Inputs fp32, output fp32.
//
// convert: Q,K -> hi/lo bf16 split (hi=RNE(x), lo=RNE(x-hi)).
// vtrans:  V -> V^T bf16 (b,d,k).
// pass1:   column stats m[b,k]=max_q s, l[b,k]=sum_q exp(s-m), q-tiles staged
//          in LDS (double-buffered), K-frags in registers.
// pass2:   out = sum_k exp(s-m[k])/l[k] * V[k,:], K-tiles staged in LDS
//          (double-buffered), V^T prefetched to regs.
// Scores: 3-term split MFMA (qh*kh + ql*kh + qh*kl) ~ fp32 precision.
//
// ws: m(128K) | l(128K) | Qhi|Qlo|Khi|Klo|Vt (8MB each) = 40.25MB

#define B_ 16
#define S_ 2048
#define D_ 128
#define SCALE 0.08838834764831845f /* 1/sqrt(128) */
#define NEG_BIG -1e30f
#define MCLAMP -1e25f /* keeps exp() at 0 for fully-masked tiles */

// Staged tile: 32 rows x (128 hi + 128 lo + 8 pad) shorts = 528B/row.
#define ROWW 264

typedef short bf16x8 __attribute__((ext_vector_type(8)));
typedef float f32x4 __attribute__((ext_vector_type(4)));
typedef unsigned short u16x4 __attribute__((ext_vector_type(4)));

static __device__ __forceinline__ unsigned short f2bf(float f) {
  unsigned int u = __builtin_bit_cast(unsigned int, f);
  u += 0x7FFFu + ((u >> 16) & 1u);  // RNE
  return (unsigned short)(u >> 16);
}
static __device__ __forceinline__ float bf2f(unsigned short h) {
  return __builtin_bit_cast(float, (unsigned int)h << 16);
}

// --------------------------------------------------------------- convert ----
__global__ __launch_bounds__(256) void sdpa_convert(
    const float* __restrict__ Qr, const float* __restrict__ Kr,
    unsigned short* __restrict__ Qhi, unsigned short* __restrict__ Qlo,
    unsigned short* __restrict__ Khi, unsigned short* __restrict__ Klo) {
  const size_t t = (size_t)blockIdx.x * 256 + threadIdx.x;
  const float* src = blockIdx.y ? Kr : Qr;
  unsigned short* hi = blockIdx.y ? Khi : Qhi;
  unsigned short* lo = blockIdx.y ? Klo : Qlo;
  f32x4 x = ((const f32x4*)src)[t];
  u16x4 ho, lv;
#pragma unroll
  for (int j = 0; j < 4; ++j) {
    unsigned short h = f2bf(x[j]);
    ho[j] = h;
    lv[j] = f2bf(x[j] - bf2f(h));
  }
  ((u16x4*)hi)[t] = ho;
  ((u16x4*)lo)[t] = lv;
}

// ---------------------------------------------------------------- vtrans ----
__global__ __launch_bounds__(256) void sdpa_vtrans(
    const float* __restrict__ Vr, unsigned short* __restrict__ Vt) {
  __shared__ unsigned short tile[D_][33];
  const int b = blockIdx.y, k0 = blockIdx.x * 32, tid = threadIdx.x;
#pragma unroll
  for (int it = 0; it < 4; ++it) {
    const int r = it * 8 + (tid >> 5);
    const int c4 = (tid & 31) * 4;
    f32x4 x = *(const f32x4*)(Vr + ((size_t)(b * S_ + k0 + r)) * D_ + c4);
#pragma unroll
    for (int j = 0; j < 4; ++j) tile[c4 + j][r] = f2bf(x[j]);
  }
  __syncthreads();
#pragma unroll
  for (int it = 0; it < 4; ++it) {
    const int d = it * 32 + (tid >> 3);
    const int kq = (tid & 7) * 4;
    u16x4 o = {tile[d][kq], tile[d][kq + 1], tile[d][kq + 2], tile[d][kq + 3]};
    *(u16x4*)(Vt + ((size_t)(b * D_ + d)) * S_ + k0 + kq) = o;
  }
}

// ----------------------------------------------------------------- pass1 ----
// grid (S/64, B), block 256. Wave w owns 16 key-columns (K-frags in regs).
// Q hi/lo tiles (32 rows) staged in LDS, double-buffered, 1 barrier/iter.
__global__ __launch_bounds__(256) void sdpa_pass1(
    const short* __restrict__ Qhi, const short* __restrict__ Qlo,
    const short* __restrict__ Khi, const short* __restrict__ Klo,
    float* __restrict__ m_ws, float* __restrict__ l_ws) {
  __shared__ __align__(16) short Qst[2][32 * ROWW];
  const int b = blockIdx.y, bx = blockIdx.x, tid = threadIdx.x;
  const int w = tid >> 6, lane = tid & 63, quad = lane >> 4, l15 = lane & 15;
  const int col = bx * 64 + w * 16 + l15;

  // K fragments for this wave's 16 columns (B operand), in registers
  const size_t koff = ((size_t)b * S_ + col) * D_ + quad * 8;
  bf16x8 kh[4], kl[4];
#pragma unroll
  for (int c = 0; c < 4; ++c) {
    kh[c] = *(const bf16x8*)(Khi + koff + c * 32);
    kl[c] = *(const bf16x8*)(Klo + koff + c * 32);
  }

  const int sr = tid >> 3, sseg = tid & 7;  // staging: row, 32B segment
  const int q_start = bx * 64;
  const int iters = (S_ - q_start) >> 5;

  {  // prolog: stage tile 0
    const short* sh = Qhi + ((size_t)(b * S_ + q_start + sr)) * D_ + sseg * 16;
    const short* sl = Qlo + ((size_t)(b * S_ + q_start + sr)) * D_ + sseg * 16;
    bf16x8 h0 = *(const bf16x8*)(sh), h1 = *(const bf16x8*)(sh + 8);
    bf16x8 L0 = *(const bf16x8*)(sl), L1 = *(const bf16x8*)(sl + 8);
    short* dst = &Qst[0][sr * ROWW + sseg * 16];
    *(bf16x8*)(dst) = h0;
    *(bf16x8*)(dst + 8) = h1;
    *(bf16x8*)(dst + 128) = L0;
    *(bf16x8*)(dst + 136) = L1;
  }
  __syncthreads();

  float m = NEG_BIG, l = 0.f;
  for (int it = 0; it < iters; ++it) {
    const int q0 = q_start + it * 32;
    const int cur = it & 1;
    const bool hasnext = (it + 1 < iters);
    bf16x8 h0, h1, L0, L1;
    if (hasnext) {  // issue next tile's global loads early
      const short* sh =
          Qhi + ((size_t)(b * S_ + q0 + 32 + sr)) * D_ + sseg * 16;
      const short* sl =
          Qlo + ((size_t)(b * S_ + q0 + 32 + sr)) * D_ + sseg * 16;
      h0 = *(const bf16x8*)(sh);
      h1 = *(const bf16x8*)(sh + 8);
      L0 = *(const bf16x8*)(sl);
      L1 = *(const bf16x8*)(sl + 8);
    }
    float sv[8];
    float tmax = NEG_BIG;
#pragma unroll
    for (int sub = 0; sub < 2; ++sub) {
      const short* row = &Qst[cur][(sub * 16 + l15) * ROWW + quad * 8];
      f32x4 acc = {0.f, 0.f, 0.f, 0.f};
#pragma unroll
      for (int c = 0; c < 4; ++c) {
        bf16x8 qhv = *(const bf16x8*)(row + c * 32);
        bf16x8 qlv = *(const bf16x8*)(row + c * 32 + 128);
        acc = __builtin_amdgcn_mfma_f32_16x16x32_bf16(qhv, kh[c], acc, 0, 0, 0);
        acc = __builtin_amdgcn_mfma_f32_16x16x32_bf16(qlv, kh[c], acc, 0, 0, 0);
        acc = __builtin_amdgcn_mfma_f32_16x16x32_bf16(qhv, kl[c], acc, 0, 0, 0);
      }
#pragma unroll
      for (int r = 0; r < 4; ++r) {
        int q = q0 + sub * 16 + quad * 4 + r;
        float s = acc[r] * SCALE;
        if (q < col) s = NEG_BIG;  // strict causal: k > q masked
        sv[sub * 4 + r] = s;
        tmax = fmaxf(tmax, s);
      }
    }
    tmax = fmaxf(tmax, __shfl_xor(tmax, 16, 64));
    tmax = fmaxf(tmax, __shfl_xor(tmax, 32, 64));
    const float mnew = fmaxf(fmaxf(m, tmax), MCLAMP);
    float tsum = 0.f;
#pragma unroll
    for (int j = 0; j < 8; ++j) tsum += __expf(sv[j] - mnew);
    tsum += __shfl_xor(tsum, 16, 64);
    tsum += __shfl_xor(tsum, 32, 64);
    l = l * __expf(m - mnew) + tsum;
    m = mnew;
    if (hasnext) {
      short* dst = &Qst[1 - cur][sr * ROWW + sseg * 16];
      *(bf16x8*)(dst) = h0;
      *(bf16x8*)(dst + 8) = h1;
      *(bf16x8*)(dst + 128) = L0;
      *(bf16x8*)(dst + 136) = L1;
    }
    __syncthreads();
  }
  if (quad == 0) {
    m_ws[b * S_ + col] = m;
    l_ws[b * S_ + col] = l;
  }
}

// ----------------------------------------------------------------- pass2 ----
// grid (S/64, B), block 256. Wave w owns 16 query-rows (Q-frags in regs).
// K hi/lo tiles staged in LDS (double-buffered); V^T prefetched to regs.
__global__ __launch_bounds__(256) void sdpa_pass2(
    const short* __restrict__ Qhi, const short* __restrict__ Qlo,
    const short* __restrict__ Khi, const short* __restrict__ Klo,
    const unsigned short* __restrict__ Vt,
    const float* __restrict__ m_ws, const float* __restrict__ l_ws,
    float* __restrict__ Out) {
  __shared__ __align__(16) short Kst[2][32 * ROWW];
  __shared__ __align__(16) float Pbuf[4][16][36];
  const int b = blockIdx.y, bx = blockIdx.x, tid = threadIdx.x;
  const int w = tid >> 6, lane = tid & 63, quad = lane >> 4, l15 = lane & 15;
  const int qrow0 = bx * 64 + w * 16;
  const int rowq = qrow0 + quad * 4;

  // Q fragments (A operand) in registers
  const size_t qoff = ((size_t)b * S_ + qrow0 + l15) * D_ + quad * 8;
  bf16x8 qh[4], ql[4];
#pragma unroll
  for (int c = 0; c < 4; ++c) {
    qh[c] = *(const bf16x8*)(Qhi + qoff + c * 32);
    ql[c] = *(const bf16x8*)(Qlo + qoff + c * 32);
  }

  f32x4 acc[8];
#pragma unroll
  for (int dt = 0; dt < 8; ++dt) acc[dt] = (f32x4){0.f, 0.f, 0.f, 0.f};

  const float* mrow = m_ws + b * S_;
  const float* lrow = l_ws + b * S_;
  const int sr = tid >> 3, sseg = tid & 7;
  const int iters = 2 * bx + 2;  // kc tiles: 0..bx*64+32 step 32

  {  // prolog: stage K tile 0
    const short* sh = Khi + ((size_t)(b * S_ + sr)) * D_ + sseg * 16;
    const short* sl = Klo + ((size_t)(b * S_ + sr)) * D_ + sseg * 16;
    bf16x8 h0 = *(const bf16x8*)(sh), h1 = *(const bf16x8*)(sh + 8);
    bf16x8 L0 = *(const bf16x8*)(sl), L1 = *(const bf16x8*)(sl + 8);
    short* dst = &Kst[0][sr * ROWW + sseg * 16];
    *(bf16x8*)(dst) = h0;
    *(bf16x8*)(dst + 8) = h1;
    *(bf16x8*)(dst + 128) = L0;
    *(bf16x8*)(dst + 136) = L1;
  }
  __syncthreads();

  for (int it = 0; it < iters; ++it) {
    const int kc = it * 32;
    const int cur = it & 1;
    const bool hasnext = (it + 1 < iters);
    // V^T prefetch for this iteration (consumed at PV below)
    bf16x8 vf[8];
#pragma unroll
    for (int dt = 0; dt < 8; ++dt)
      vf[dt] = *(const bf16x8*)(Vt + ((size_t)b * D_ + dt * 16 + l15) * S_ +
                                kc + quad * 8);
    // column stats for this iteration
    const float mc0 = mrow[kc + l15], mc1 = mrow[kc + 16 + l15];
    const float rl0 = 1.0f / lrow[kc + l15], rl1 = 1.0f / lrow[kc + 16 + l15];
    // next K tile's global loads
    bf16x8 h0, h1, L0, L1;
    if (hasnext) {
      const short* sh =
          Khi + ((size_t)(b * S_ + kc + 32 + sr)) * D_ + sseg * 16;
      const short* sl =
          Klo + ((size_t)(b * S_ + kc + 32 + sr)) * D_ + sseg * 16;
      h0 = *(const bf16x8*)(sh);
      h1 = *(const bf16x8*)(sh + 8);
      L0 = *(const bf16x8*)(sl);
      L1 = *(const bf16x8*)(sl + 8);
    }
    // scores from LDS tile
#pragma unroll
    for (int sub = 0; sub < 2; ++sub) {
      const short* row = &Kst[cur][(sub * 16 + l15) * ROWW + quad * 8];
      f32x4 sa = {0.f, 0.f, 0.f, 0.f};
#pragma unroll
      for (int c = 0; c < 4; ++c) {
        bf16x8 khv = *(const bf16x8*)(row + c * 32);
        bf16x8 klv = *(const bf16x8*)(row + c * 32 + 128);
        sa = __builtin_amdgcn_mfma_f32_16x16x32_bf16(qh[c], khv, sa, 0, 0, 0);
        sa = __builtin_amdgcn_mfma_f32_16x16x32_bf16(ql[c], khv, sa, 0, 0, 0);
        sa = __builtin_amdgcn_mfma_f32_16x16x32_bf16(qh[c], klv, sa, 0, 0, 0);
      }
      const int colk = kc + sub * 16 + l15;
      const float mc = sub ? mc1 : mc0;
      const float rl = sub ? rl1 : rl0;
#pragma unroll
      for (int r = 0; r < 4; ++r) {
        float p = (colk <= rowq + r) ? __expf(sa[r] * SCALE - mc) * rl : 0.f;
        Pbuf[w][quad * 4 + r][sub * 16 + l15] = p;  // C-layout -> LDS
      }
    }
    // C-layout (fp32, LDS) -> A-fragment (bf16, regs); wave-private
    const float* pr = &Pbuf[w][l15][quad * 8];
    f32x4 p0 = *(const f32x4*)(pr);
    f32x4 p1 = *(const f32x4*)(pr + 4);
    bf16x8 pa;
#pragma unroll
    for (int j = 0; j < 4; ++j) {
      pa[j] = (short)f2bf(p0[j]);
      pa[j + 4] = (short)f2bf(p1[j]);
    }
#pragma unroll
    for (int dt = 0; dt < 8; ++dt)
      acc[dt] = __builtin_amdgcn_mfma_f32_16x16x32_bf16(pa, vf[dt], acc[dt],
                                                        0, 0, 0);
    if (hasnext) {
      short* dst = &Kst[1 - cur][sr * ROWW + sseg * 16];
      *(bf16x8*)(dst) = h0;
      *(bf16x8*)(dst + 8) = h1;
      *(bf16x8*)(dst + 128) = L0;
      *(bf16x8*)(dst + 136) = L1;
    }
    __syncthreads();
  }
  // epilogue: C-layout -> fp32 global
#pragma unroll
  for (int r = 0; r < 4; ++r) {
    float* op = Out + ((size_t)b * S_ + rowq + r) * D_ + l15;
#pragma unroll
    for (int dt = 0; dt < 8; ++dt) op[dt * 16] = acc[dt][r];
  }
}

extern "C" void kernel_launch(void* const* d_in, const int* in_sizes, int n_in,
                              void* d_out, int out_size, void* d_ws, size_t ws_size,
                              hipStream_t stream) {
  char* w = (char*)d_ws;
  float* m_ws = (float*)w;
  float* l_ws = (float*)(w + 131072);
  char* p = w + 262144;
  const size_t TSZ = (size_t)B_ * S_ * D_ * 2;  // 8 MB per bf16 tensor
  unsigned short* Qhi = (unsigned short*)(p);
  unsigned short* Qlo = (unsigned short*)(p + TSZ);
  unsigned short* Khi = (unsigned short*)(p + 2 * TSZ);
  unsigned short* Klo = (unsigned short*)(p + 3 * TSZ);
  unsigned short* Vt  = (unsigned short*)(p + 4 * TSZ);

  sdpa_convert<<<dim3((B_ * S_ * D_ / 4) / 256, 2), 256, 0, stream>>>(
      (const float*)d_in[0], (const float*)d_in[1], Qhi, Qlo, Khi, Klo);
  sdpa_vtrans<<<dim3(S_ / 32, B_), 256, 0, stream>>>((const float*)d_in[2], Vt);
  sdpa_pass1<<<dim3(S_ / 64, B_), 256, 0, stream>>>(
      (const short*)Qhi, (const short*)Qlo, (const short*)Khi,
      (const short*)Klo, m_ws, l_ws);
  sdpa_pass2<<<dim3(S_ / 64, B_), 256, 0, stream>>>(
      (const short*)Qhi, (const short*)Qlo, (const short*)Khi,
      (const short*)Klo, Vt, m_ws, l_ws, (float*)d_out);
}